// Round 2
// baseline (14735.071 us; speedup 1.0000x reference)
//
#include <hip/hip_runtime.h>
#include <math.h>

#define BN_EPS 1e-3f

__device__ __forceinline__ float hsig(float x) {
    return fminf(fmaxf(0.2f * x + 0.5f, 0.f), 1.f);
}

// ---------------------------------------------------------------------------
// Fused gate GEMM + LSTM state update + optional BN write, one timestep.
// Columns are gate-interleaved: block covers FT features x 4 gates = COLS
// columns; LDS col c -> (f_local = c>>2, gate = c&3), global W col
// n = gate*F + f0 + f_local. Each thread's TN cols = FPT features x 4 gates,
// so the i/f/c/o combine is thread-local in the epilogue.
// h is ping-ponged across timesteps (h_old read, h_new written) since blocks
// read neighbor l-rows. c_state is in-place (each (b,l,f) owned by 1 block).
// grid: (F/FT, L/LT, B), block: (LT/TM)*(COLS/TN) == 256 threads.
// ---------------------------------------------------------------------------
template<int FT, int LT, int TM, int TN>
__global__ __launch_bounds__(256)
void gate_gemm_fused(const float* __restrict__ xt,  // layer input at timestep t
                     long xt_bstride,               // batch stride of xt
                     int Cin,
                     const float* __restrict__ Wx,  // [3, Cin, 4F]
                     const float* __restrict__ h_old, // [B, L, F]
                     int F,
                     const float* __restrict__ Wh,  // [3, F, 4F]
                     const float* __restrict__ bias,// [4F]
                     float* __restrict__ c_state,   // [B, L, F] in-place
                     float* __restrict__ h_new,     // [B, L, F]
                     float* __restrict__ bn_out,    // may be null; + l*F + f
                     long bn_bstride,               // batch stride of bn_out
                     const float* __restrict__ bn_g, const float* __restrict__ bn_b,
                     const float* __restrict__ bn_m, const float* __restrict__ bn_v,
                     int L)
{
    constexpr int COLS = FT * 4;
    constexpr int CT   = COLS / TN;   // col thread groups
    constexpr int FPT  = TN / 4;      // features per thread

    __shared__ float As[LT + 2][17];                  // +1 pad kills stride-16 conflicts
    __shared__ __align__(16) float Ws[3][16][COLS];

    const int f0 = blockIdx.x * FT;
    const int l0 = blockIdx.y * LT;
    const int b  = blockIdx.z;
    const int tid = threadIdx.x;
    const int tn = tid % CT;
    const int tm = tid / CT;

    float acc[TM][TN];
#pragma unroll
    for (int i = 0; i < TM; ++i)
#pragma unroll
        for (int j = 0; j < TN; ++j) acc[i][j] = 0.f;

    for (int src = 0; src < 2; ++src) {
        const float* A = (src == 0) ? (xt + (long)b * xt_bstride)
                                    : (h_old + (long)b * L * F);
        const float* W = (src == 0) ? Wx : Wh;
        const int C = (src == 0) ? Cin : F;
        const int N4 = 4 * F;

        for (int c0 = 0; c0 < C; c0 += 16) {
            // stage A rows l0-1 .. l0+LT (LT+2 rows) x 16 channels
            for (int idx = tid; idx < (LT + 2) * 16; idx += 256) {
                int r = idx >> 4, ci = idx & 15;
                int l = l0 - 1 + r;
                int ch = c0 + ci;
                float v = 0.f;
                if (l >= 0 && l < L && ch < C) v = A[(long)l * C + ch];
                As[r][ci] = v;
            }
            // stage W [3][16][COLS] with gate-interleaved column permutation
            for (int idx = tid; idx < 3 * 16 * COLS; idx += 256) {
                int k   = idx / (16 * COLS);
                int rem = idx % (16 * COLS);
                int ci  = rem / COLS;
                int c   = rem % COLS;
                int ch  = c0 + ci;
                int n   = (c & 3) * F + f0 + (c >> 2);
                float v = 0.f;
                if (ch < C) v = W[((long)k * C + ch) * N4 + n];
                Ws[k][ci][c] = v;
            }
            __syncthreads();

#pragma unroll
            for (int k = 0; k < 3; ++k) {
#pragma unroll 4
                for (int ci = 0; ci < 16; ++ci) {
                    float a[TM];
#pragma unroll
                    for (int i = 0; i < TM; ++i) a[i] = As[tm * TM + i + k][ci];
#pragma unroll
                    for (int j4 = 0; j4 < TN / 4; ++j4) {
                        const float4 w4 = *(const float4*)&Ws[k][ci][tn * TN + j4 * 4];
#pragma unroll
                        for (int i = 0; i < TM; ++i) {
                            acc[i][j4 * 4 + 0] += a[i] * w4.x;
                            acc[i][j4 * 4 + 1] += a[i] * w4.y;
                            acc[i][j4 * 4 + 2] += a[i] * w4.z;
                            acc[i][j4 * 4 + 3] += a[i] * w4.w;
                        }
                    }
                }
            }
            __syncthreads();
        }
    }

    // epilogue: bias, gates, state update, optional BN write
    float bi[FPT][4], bsc[FPT], bsh[FPT];
#pragma unroll
    for (int fi = 0; fi < FPT; ++fi) {
        int f = f0 + tn * FPT + fi;
#pragma unroll
        for (int g4 = 0; g4 < 4; ++g4) bi[fi][g4] = bias[g4 * F + f];
        if (bn_out) {
            float sc = bn_g[f] * rsqrtf(bn_v[f] + BN_EPS);
            bsc[fi] = sc;
            bsh[fi] = bn_b[f] - bn_m[f] * sc;
        }
    }

#pragma unroll
    for (int i = 0; i < TM; ++i) {
        int l = l0 + tm * TM + i;
        long base = ((long)b * L + l) * F;
#pragma unroll
        for (int fi = 0; fi < FPT; ++fi) {
            int f = f0 + tn * FPT + fi;
            float gi_ = acc[i][fi * 4 + 0] + bi[fi][0];
            float gf_ = acc[i][fi * 4 + 1] + bi[fi][1];
            float gc_ = acc[i][fi * 4 + 2] + bi[fi][2];
            float go_ = acc[i][fi * 4 + 3] + bi[fi][3];
            float cold = c_state[base + f];
            float cn = hsig(gf_) * cold + hsig(gi_) * fmaxf(gc_, 0.f);
            float hn = hsig(go_) * fmaxf(cn, 0.f);
            c_state[base + f] = cn;
            h_new[base + f] = hn;
            if (bn_out)
                bn_out[(long)b * bn_bstride + (long)l * F + f] = hn * bsc[fi] + bsh[fi];
        }
    }
}

// ---------------------------------------------------------------------------
// Split-K dense for skinny-M GEMM (M=32): partials[kchunk][32][N].
// grid: (N/128, K/KT), block 256. KT <= 256.
// ---------------------------------------------------------------------------
__global__ __launch_bounds__(256)
void dense_partial(const float* __restrict__ A,   // [32, K]
                   const float* __restrict__ Wt,  // [K, N]
                   float* __restrict__ partials,  // [nK, 32, N]
                   int K, int N, int KT)
{
    __shared__ __align__(16) float A_s[256 * 32];  // [k][m]
    const int n0 = blockIdx.x * 128;
    const int k0 = blockIdx.y * KT;
    const int tid = threadIdx.x;

    for (int idx = tid; idx < KT * 32; idx += 256) {
        int k = idx >> 5, m = idx & 31;
        A_s[idx] = A[(long)m * K + k0 + k];
    }
    __syncthreads();

    const int nl = tid & 127;
    const int msel = tid >> 7;   // 0 or 1 -> m 0..15 or 16..31
    float acc[16];
#pragma unroll
    for (int i = 0; i < 16; ++i) acc[i] = 0.f;

    for (int k = 0; k < KT; ++k) {
        float wv = Wt[(long)(k0 + k) * N + n0 + nl];
        const float4* ap = (const float4*)&A_s[k * 32 + msel * 16];
        float4 a0 = ap[0], a1 = ap[1], a2 = ap[2], a3 = ap[3];
        acc[0]  += a0.x * wv; acc[1]  += a0.y * wv; acc[2]  += a0.z * wv; acc[3]  += a0.w * wv;
        acc[4]  += a1.x * wv; acc[5]  += a1.y * wv; acc[6]  += a1.z * wv; acc[7]  += a1.w * wv;
        acc[8]  += a2.x * wv; acc[9]  += a2.y * wv; acc[10] += a2.z * wv; acc[11] += a2.w * wv;
        acc[12] += a3.x * wv; acc[13] += a3.y * wv; acc[14] += a3.z * wv; acc[15] += a3.w * wv;
    }

#pragma unroll
    for (int mm = 0; mm < 16; ++mm)
        partials[((long)blockIdx.y * 32 + msel * 16 + mm) * N + n0 + nl] = acc[mm];
}

// out[m,n] = relu(bias[n] + sum_j partials[j,m,n]); grid: 32*N/256
__global__ __launch_bounds__(256)
void dense_reduce_relu(const float* __restrict__ partials,
                       const float* __restrict__ bias,
                       float* __restrict__ out, int N, int nK)
{
    int idx = blockIdx.x * 256 + threadIdx.x;
    int m = idx / N, n = idx % N;
    float s = bias[n];
    for (int j = 0; j < nK; ++j) s += partials[((long)j * 32 + m) * N + n];
    out[idx] = fmaxf(s, 0.f);
}

// simple dense+relu for the small D2 (K=1024, N=512)
__global__ __launch_bounds__(256)
void dense_relu(const float* __restrict__ A,   // [M, K]
                const float* __restrict__ Wt,  // [K, N]
                const float* __restrict__ bias,
                float* __restrict__ out, int K, int N)
{
    __shared__ float As[256];
    int n = blockIdx.x * 256 + threadIdx.x;
    int m = blockIdx.y;
    float acc = 0.f;
    for (int k0 = 0; k0 < K; k0 += 256) {
        __syncthreads();
        As[threadIdx.x] = A[(long)m * K + k0 + threadIdx.x];
        __syncthreads();
#pragma unroll 8
        for (int kk = 0; kk < 256; ++kk)
            acc += As[kk] * Wt[(long)(k0 + kk) * N + n];
    }
    out[(long)m * N + n] = fmaxf(acc + bias[n], 0.f);
}

// Final dense (512 -> 5) + softmax. grid = 32 (batch), block = 64 (one wave).
__global__ __launch_bounds__(64)
void dense_softmax(const float* __restrict__ A,  // [32, 512]
                   const float* __restrict__ W,  // [512, 5]
                   const float* __restrict__ bias,
                   float* __restrict__ out)      // [32, 5]
{
    int b = blockIdx.x;
    int tid = threadIdx.x;
    __shared__ float logits[5];

    float part[5] = {0.f, 0.f, 0.f, 0.f, 0.f};
    for (int k = tid; k < 512; k += 64) {
        float a = A[b * 512 + k];
#pragma unroll
        for (int j = 0; j < 5; ++j) part[j] += a * W[k * 5 + j];
    }
#pragma unroll
    for (int j = 0; j < 5; ++j) {
        float v = part[j];
        for (int off = 32; off; off >>= 1) v += __shfl_down(v, off);
        if (tid == 0) logits[j] = v + bias[j];
    }
    __syncthreads();
    if (tid == 0) {
        float mx = logits[0];
        for (int j = 1; j < 5; ++j) mx = fmaxf(mx, logits[j]);
        float s = 0.f, e[5];
        for (int j = 0; j < 5; ++j) { e[j] = expf(logits[j] - mx); s += e[j]; }
        for (int j = 0; j < 5; ++j) out[b * 5 + j] = e[j] / s;
    }
}

extern "C" void kernel_launch(void* const* d_in, const int* in_sizes, int n_in,
                              void* d_out, int out_size, void* d_ws, size_t ws_size,
                              hipStream_t stream)
{
    const int B = 32, T = 32, L = 128;
    const int F1 = 64, F2 = 128, F3 = 256;

    const float* x   = (const float*)d_in[0];
    const float* Wx1 = (const float*)d_in[1];
    const float* Wh1 = (const float*)d_in[2];
    const float* b1  = (const float*)d_in[3];
    const float* Wx2 = (const float*)d_in[4];
    const float* Wh2 = (const float*)d_in[5];
    const float* b2  = (const float*)d_in[6];
    const float* Wx3 = (const float*)d_in[7];
    const float* Wh3 = (const float*)d_in[8];
    const float* b3  = (const float*)d_in[9];
    const float* g1  = (const float*)d_in[10];
    const float* be1 = (const float*)d_in[11];
    const float* m1  = (const float*)d_in[12];
    const float* v1  = (const float*)d_in[13];
    const float* g2  = (const float*)d_in[14];
    const float* be2 = (const float*)d_in[15];
    const float* m2  = (const float*)d_in[16];
    const float* v2  = (const float*)d_in[17];
    const float* g3  = (const float*)d_in[18];
    const float* be3 = (const float*)d_in[19];
    const float* m3  = (const float*)d_in[20];
    const float* v3  = (const float*)d_in[21];
    const float* D1  = (const float*)d_in[22];  // [32768, 1024]
    const float* db1 = (const float*)d_in[23];
    const float* D2  = (const float*)d_in[24];  // [1024, 512]
    const float* db2 = (const float*)d_in[25];
    const float* D3  = (const float*)d_in[26];  // [512, 5]
    const float* db3 = (const float*)d_in[27];
    (void)in_sizes; (void)n_in; (void)out_size; (void)ws_size;

    float* ws = (float*)d_ws;
    size_t off = 0;
    float* h1seq = ws + off; off += (size_t)B * T * L * F1;   // 8.39M floats
    float* h2seq = ws + off; off += (size_t)B * T * L * F2;   // 16.78M
    float* hping = ws + off; off += (size_t)B * L * F3;       // 1.05M (max F)
    float* hpong = ws + off; off += (size_t)B * L * F3;
    float* cst   = ws + off; off += (size_t)B * L * F3;
    float* h3bn  = ws + off; off += (size_t)B * L * F3;
    // dense scratch aliases h1seq (dead after layer-2 gemms complete)
    float* partials = h1seq;                                  // 128*32*1024 = 4.19M
    float* a1 = h1seq + (size_t)128 * 32 * 1024;              // 32K
    float* a2 = a1 + (size_t)B * 1024;                        // 16K

    // ---------------- Layer 1: Cin=1, F=64 ----------------
    hipMemsetAsync(hping, 0, (size_t)B * L * F1 * sizeof(float), stream);
    hipMemsetAsync(cst, 0, (size_t)B * L * F1 * sizeof(float), stream);
    {
        float* ha = hping; float* hb = hpong;
        dim3 grid(F1 / 16, L / 64, B);
        for (int t = 0; t < T; ++t) {
            gate_gemm_fused<16, 64, 4, 4><<<grid, 256, 0, stream>>>(
                x + (long)t * L, (long)T * L, 1, Wx1, ha, F1, Wh1, b1,
                cst, hb, h1seq + (long)t * L * F1, (long)T * L * F1,
                g1, be1, m1, v1, L);
            float* tmp = ha; ha = hb; hb = tmp;
        }
    }

    // ---------------- Layer 2: Cin=64, F=128 ----------------
    hipMemsetAsync(hping, 0, (size_t)B * L * F2 * sizeof(float), stream);
    hipMemsetAsync(cst, 0, (size_t)B * L * F2 * sizeof(float), stream);
    {
        float* ha = hping; float* hb = hpong;
        dim3 grid(F2 / 16, L / 64, B);
        for (int t = 0; t < T; ++t) {
            gate_gemm_fused<16, 64, 4, 4><<<grid, 256, 0, stream>>>(
                h1seq + (long)t * L * F1, (long)T * L * F1, F1, Wx2, ha, F2, Wh2, b2,
                cst, hb, h2seq + (long)t * L * F2, (long)T * L * F2,
                g2, be2, m2, v2, L);
            float* tmp = ha; ha = hb; hb = tmp;
        }
    }

    // ---------------- Layer 3: Cin=128, F=256, last h only ----------------
    hipMemsetAsync(hping, 0, (size_t)B * L * F3 * sizeof(float), stream);
    hipMemsetAsync(cst, 0, (size_t)B * L * F3 * sizeof(float), stream);
    {
        float* ha = hping; float* hb = hpong;
        dim3 grid(F3 / 32, L / 128, B);
        for (int t = 0; t < T; ++t) {
            gate_gemm_fused<32, 128, 8, 8><<<grid, 256, 0, stream>>>(
                h2seq + (long)t * L * F2, (long)T * L * F2, F2, Wx3, ha, F3, Wh3, b3,
                cst, hb, (t == T - 1) ? h3bn : nullptr, (long)L * F3,
                g3, be3, m3, v3, L);
            float* tmp = ha; ha = hb; hb = tmp;
        }
    }

    // ---------------- Dense head ----------------
    {
        const int K = L * F3;           // 32768
        const int KT = 256, nK = K / KT; // 128
        dense_partial<<<dim3(1024 / 128, nK), 256, 0, stream>>>(h3bn, D1, partials, K, 1024, KT);
        dense_reduce_relu<<<(B * 1024) / 256, 256, 0, stream>>>(partials, db1, a1, 1024, nK);
    }
    dense_relu<<<dim3(512 / 256, B), 256, 0, stream>>>(a1, D2, db2, a2, 1024, 512);
    dense_softmax<<<B, 64, 0, stream>>>(a2, D3, db3, (float*)d_out);
}

// Round 3
// 3011.682 us; speedup vs baseline: 4.8926x; 4.8926x over previous
//
#include <hip/hip_runtime.h>
#include <math.h>

#define BN_EPS 1e-3f

typedef unsigned short ushort;
typedef unsigned int uint;
typedef __attribute__((ext_vector_type(8))) short bf16x8;
typedef __attribute__((ext_vector_type(4))) float f32x4;

__device__ __forceinline__ float hsig(float x) {
    return fminf(fmaxf(0.2f * x + 0.5f, 0.f), 1.f);
}
__device__ __forceinline__ ushort f2bf(float f) {
    uint u = __float_as_uint(f);
    u += 0x7fffu + ((u >> 16) & 1u);   // RNE
    return (ushort)(u >> 16);
}

// ---------------------------------------------------------------------------
// pack_w: pre-transform fp32 weights [3,Cin,4F]+[3,F,4F] into bf16
// fragment-order layout: wp[nblk][step][slot(512)][8], slot = (gate*2+wn)*64 +
// q*16 + r; element = W[k = step*32 + q*8 + j][n = gate*F + nblk*32 + wn*16 + r]
// K packing: steps [0,S0) from Wx (k_abs < 3*Cin valid, else 0), rest from Wh.
// grid: (F/32, S), block 256.
// ---------------------------------------------------------------------------
__global__ __launch_bounds__(256)
void pack_w(const float* __restrict__ Wx, int Cin,
            const float* __restrict__ Wh, int F,
            uint4* __restrict__ wp, int S0, int S)
{
    __shared__ ushort Wt[32][136];
    const int nblk = blockIdx.x, step = blockIdx.y;
    const int tid = threadIdx.x;
    const int N4 = 4 * F;

    for (int idx = tid; idx < 32 * 128; idx += 256) {
        int kk = idx >> 7, c = idx & 127;
        int gate = c >> 5, fl = c & 31;
        int n = gate * F + nblk * 32 + fl;
        float v = 0.f;
        if (step < S0) {
            int ka = step * 32 + kk;
            if (ka < 3 * Cin) v = Wx[(long)ka * N4 + n];
        } else {
            int ka = (step - S0) * 32 + kk;
            v = Wh[(long)ka * N4 + n];
        }
        Wt[kk][c] = f2bf(v);
    }
    __syncthreads();

    for (int s = tid; s < 512; s += 256) {
        int colgrp = s >> 6, qq = (s >> 4) & 3, rr = s & 15;
        int gate = colgrp >> 1, wn = colgrp & 1;
        int c = gate * 32 + wn * 16 + rr;
        ushort tmp[8];
#pragma unroll
        for (int j = 0; j < 8; ++j) tmp[j] = Wt[qq * 8 + j][c];
        wp[(long)(nblk * S + step) * 512 + s] = *(const uint4*)tmp;
    }
}

// ---------------------------------------------------------------------------
// Fused MFMA gate GEMM + LSTM update + optional BN write, one timestep.
// Block: 256 thr = 4 waves (wm in {0,1} x wn in {0,1}); tile LT(l) x 128 cols
// where 128 cols = 4 gates x 32 features (block features f0..f0+31).
// Wave covers LT/2 rows (MT=LT/32 m-frags) and, per gate, 16 features
// (f = f0 + wn*16 + lane&15). n-frag index == gate -> each lane's 4 acc frags
// are the 4 gates of ONE feature: gate combine is thread-local.
// LDS is fragment-order: lane's 16B at base + lane*16 (conflict-free b128).
// K = concat(src0 = im2col(layer input), src1 = im2col(h_old)); B from wp.
// ---------------------------------------------------------------------------
template<int LT, bool CIN1, bool BNF32>
__global__ __launch_bounds__(256)
void gate_mfma(const void* __restrict__ a0_base,  // layer input at timestep t
               long a0_bstride,                   // batch stride (elements)
               int C0, int S0, int S,
               const ushort* __restrict__ h_old,  // bf16 [B,L,F]
               int F,
               const uint4* __restrict__ wp,      // packed weights
               const float* __restrict__ bias,    // [4F]
               float* __restrict__ c_state,       // fp32 [B,L,F] in-place
               ushort* __restrict__ h_new,        // bf16 [B,L,F]
               void* __restrict__ bn_out,         // may be null
               long bn_bstride,
               const float* __restrict__ bn_g, const float* __restrict__ bn_b,
               const float* __restrict__ bn_m, const float* __restrict__ bn_v,
               int L)
{
    constexpr int MT = LT / 32;        // m-frags per wave
    constexpr int ASLOTS = LT * 4;     // 16B slots per A step-tile

    __shared__ ushort As[3][ASLOTS * 8];
    __shared__ ushort Bs[3][512 * 8];

    const int tid = threadIdx.x;
    const int lane = tid & 63;
    const int wave = tid >> 6;
    const int wm = wave >> 1, wn = wave & 1;
    const int q = lane >> 4, r = lane & 15;
    const int f0 = blockIdx.x * 32;
    const int l0 = blockIdx.y * LT;
    const int b = blockIdx.z;

    f32x4 acc[MT][4];
#pragma unroll
    for (int mt = 0; mt < MT; ++mt)
#pragma unroll
        for (int g = 0; g < 4; ++g) acc[mt][g] = (f32x4)(0.f);

    for (int r0 = 0; r0 < S; r0 += 3) {
        const int ns = (S - r0 < 3) ? (S - r0) : 3;
        __syncthreads();
        for (int ss = 0; ss < ns; ++ss) {
            const int step = r0 + ss;
            // ---- B stage: coalesced 16B copies from packed weights ----
            for (int s = tid; s < 512; s += 256)
                ((uint4*)Bs[ss])[s] = wp[((long)blockIdx.x * S + step) * 512 + s];
            // ---- A stage: im2col into fragment order ----
            for (int s = tid; s < ASLOTS; s += 256) {
                const int mtile = s >> 6, within = s & 63;
                const int qq = within >> 4, rr = within & 15;
                const int row = mtile * 16 + rr;
                if (CIN1 && step < S0) {
                    const float* xb = (const float*)a0_base + (long)b * a0_bstride;
#pragma unroll
                    for (int j = 0; j < 8; ++j) {
                        ushort v = 0;
                        int k = qq * 8 + j;
                        if (k < 3) {
                            int l = l0 + row - 1 + k;
                            if (l >= 0 && l < L) v = f2bf(xb[l]);
                        }
                        As[ss][s * 8 + j] = v;
                    }
                } else {
                    const ushort* Ab;
                    int C, local;
                    if (step < S0) {
                        Ab = (const ushort*)a0_base + (long)b * a0_bstride;
                        C = C0; local = step;
                    } else {
                        Ab = h_old + (long)b * L * F;
                        C = F; local = step - S0;
                    }
                    const int tap = (local * 32) / C;
                    const int c0 = (local * 32) % C;
                    const int l = l0 + row - 1 + tap;
                    uint4 val = {0u, 0u, 0u, 0u};
                    if (l >= 0 && l < L)
                        val = *(const uint4*)&Ab[(long)l * C + c0 + qq * 8];
                    ((uint4*)As[ss])[s] = val;
                }
            }
        }
        __syncthreads();
        for (int ss = 0; ss < ns; ++ss) {
            bf16x8 af[MT], bfr[4];
#pragma unroll
            for (int mt = 0; mt < MT; ++mt)
                af[mt] = *(const bf16x8*)&As[ss][((wm * MT + mt) * 64 + lane) * 8];
#pragma unroll
            for (int g = 0; g < 4; ++g)
                bfr[g] = *(const bf16x8*)&Bs[ss][((g * 2 + wn) * 64 + lane) * 8];
#pragma unroll
            for (int mt = 0; mt < MT; ++mt)
#pragma unroll
                for (int g = 0; g < 4; ++g)
                    acc[mt][g] = __builtin_amdgcn_mfma_f32_16x16x32_bf16(
                        af[mt], bfr[g], acc[mt][g], 0, 0, 0);
        }
    }

    // ---- epilogue: bias, gates, state update, optional BN ----
    const int f = f0 + wn * 16 + r;
    const float b_i = bias[f], b_f = bias[F + f];
    const float b_c = bias[2 * F + f], b_o = bias[3 * F + f];
    float sc = 0.f, sh = 0.f;
    if (bn_out) {
        sc = bn_g[f] * rsqrtf(bn_v[f] + BN_EPS);
        sh = bn_b[f] - bn_m[f] * sc;
    }
#pragma unroll
    for (int mt = 0; mt < MT; ++mt) {
#pragma unroll
        for (int reg = 0; reg < 4; ++reg) {
            const int l = l0 + wm * (LT / 2) + mt * 16 + q * 4 + reg;
            const long idx = ((long)b * L + l) * F + f;
            float gi = acc[mt][0][reg] + b_i;
            float gf = acc[mt][1][reg] + b_f;
            float gc = acc[mt][2][reg] + b_c;
            float go = acc[mt][3][reg] + b_o;
            float cold = c_state[idx];
            float cn = hsig(gf) * cold + hsig(gi) * fmaxf(gc, 0.f);
            float hn = hsig(go) * fmaxf(cn, 0.f);
            c_state[idx] = cn;
            h_new[idx] = f2bf(hn);
            if (bn_out) {
                float bv = hn * sc + sh;
                if (BNF32)
                    ((float*)bn_out)[(long)b * bn_bstride + (long)l * F + f] = bv;
                else
                    ((ushort*)bn_out)[(long)b * bn_bstride + (long)l * F + f] = f2bf(bv);
            }
        }
    }
}

// ---------------------------------------------------------------------------
// Dense head (fp32, unchanged from round 1)
// ---------------------------------------------------------------------------
__global__ __launch_bounds__(256)
void dense_partial(const float* __restrict__ A, const float* __restrict__ Wt,
                   float* __restrict__ partials, int K, int N, int KT)
{
    __shared__ __align__(16) float A_s[256 * 32];
    const int n0 = blockIdx.x * 128;
    const int k0 = blockIdx.y * KT;
    const int tid = threadIdx.x;

    for (int idx = tid; idx < KT * 32; idx += 256) {
        int k = idx >> 5, m = idx & 31;
        A_s[idx] = A[(long)m * K + k0 + k];
    }
    __syncthreads();

    const int nl = tid & 127;
    const int msel = tid >> 7;
    float acc[16];
#pragma unroll
    for (int i = 0; i < 16; ++i) acc[i] = 0.f;

    for (int k = 0; k < KT; ++k) {
        float wv = Wt[(long)(k0 + k) * N + n0 + nl];
        const float4* ap = (const float4*)&A_s[k * 32 + msel * 16];
        float4 a0 = ap[0], a1 = ap[1], a2 = ap[2], a3 = ap[3];
        acc[0]  += a0.x * wv; acc[1]  += a0.y * wv; acc[2]  += a0.z * wv; acc[3]  += a0.w * wv;
        acc[4]  += a1.x * wv; acc[5]  += a1.y * wv; acc[6]  += a1.z * wv; acc[7]  += a1.w * wv;
        acc[8]  += a2.x * wv; acc[9]  += a2.y * wv; acc[10] += a2.z * wv; acc[11] += a2.w * wv;
        acc[12] += a3.x * wv; acc[13] += a3.y * wv; acc[14] += a3.z * wv; acc[15] += a3.w * wv;
    }
#pragma unroll
    for (int mm = 0; mm < 16; ++mm)
        partials[((long)blockIdx.y * 32 + msel * 16 + mm) * N + n0 + nl] = acc[mm];
}

__global__ __launch_bounds__(256)
void dense_reduce_relu(const float* __restrict__ partials,
                       const float* __restrict__ bias,
                       float* __restrict__ out, int N, int nK)
{
    int idx = blockIdx.x * 256 + threadIdx.x;
    int m = idx / N, n = idx % N;
    float s = bias[n];
    for (int j = 0; j < nK; ++j) s += partials[((long)j * 32 + m) * N + n];
    out[idx] = fmaxf(s, 0.f);
}

__global__ __launch_bounds__(256)
void dense_relu(const float* __restrict__ A, const float* __restrict__ Wt,
                const float* __restrict__ bias, float* __restrict__ out,
                int K, int N)
{
    __shared__ float As[256];
    int n = blockIdx.x * 256 + threadIdx.x;
    int m = blockIdx.y;
    float acc = 0.f;
    for (int k0 = 0; k0 < K; k0 += 256) {
        __syncthreads();
        As[threadIdx.x] = A[(long)m * K + k0 + threadIdx.x];
        __syncthreads();
#pragma unroll 8
        for (int kk = 0; kk < 256; ++kk)
            acc += As[kk] * Wt[(long)(k0 + kk) * N + n];
    }
    out[(long)m * N + n] = fmaxf(acc + bias[n], 0.f);
}

__global__ __launch_bounds__(64)
void dense_softmax(const float* __restrict__ A, const float* __restrict__ W,
                   const float* __restrict__ bias, float* __restrict__ out)
{
    int b = blockIdx.x;
    int tid = threadIdx.x;
    __shared__ float logits[5];

    float part[5] = {0.f, 0.f, 0.f, 0.f, 0.f};
    for (int k = tid; k < 512; k += 64) {
        float a = A[b * 512 + k];
#pragma unroll
        for (int j = 0; j < 5; ++j) part[j] += a * W[k * 5 + j];
    }
#pragma unroll
    for (int j = 0; j < 5; ++j) {
        float v = part[j];
        for (int off = 32; off; off >>= 1) v += __shfl_down(v, off);
        if (tid == 0) logits[j] = v + bias[j];
    }
    __syncthreads();
    if (tid == 0) {
        float mx = logits[0];
        for (int j = 1; j < 5; ++j) mx = fmaxf(mx, logits[j]);
        float s = 0.f, e[5];
        for (int j = 0; j < 5; ++j) { e[j] = expf(logits[j] - mx); s += e[j]; }
        for (int j = 0; j < 5; ++j) out[b * 5 + j] = e[j] / s;
    }
}

extern "C" void kernel_launch(void* const* d_in, const int* in_sizes, int n_in,
                              void* d_out, int out_size, void* d_ws, size_t ws_size,
                              hipStream_t stream)
{
    const int B = 32, T = 32, L = 128;
    const int F1 = 64, F2 = 128, F3 = 256;

    const float* x   = (const float*)d_in[0];
    const float* Wx1 = (const float*)d_in[1];
    const float* Wh1 = (const float*)d_in[2];
    const float* b1  = (const float*)d_in[3];
    const float* Wx2 = (const float*)d_in[4];
    const float* Wh2 = (const float*)d_in[5];
    const float* b2  = (const float*)d_in[6];
    const float* Wx3 = (const float*)d_in[7];
    const float* Wh3 = (const float*)d_in[8];
    const float* b3  = (const float*)d_in[9];
    const float* g1  = (const float*)d_in[10];
    const float* be1 = (const float*)d_in[11];
    const float* m1  = (const float*)d_in[12];
    const float* v1  = (const float*)d_in[13];
    const float* g2  = (const float*)d_in[14];
    const float* be2 = (const float*)d_in[15];
    const float* m2  = (const float*)d_in[16];
    const float* v2  = (const float*)d_in[17];
    const float* g3  = (const float*)d_in[18];
    const float* be3 = (const float*)d_in[19];
    const float* m3  = (const float*)d_in[20];
    const float* v3  = (const float*)d_in[21];
    const float* D1  = (const float*)d_in[22];
    const float* db1 = (const float*)d_in[23];
    const float* D2  = (const float*)d_in[24];
    const float* db2 = (const float*)d_in[25];
    const float* D3  = (const float*)d_in[26];
    const float* db3 = (const float*)d_in[27];
    (void)in_sizes; (void)n_in; (void)out_size; (void)ws_size;

    // ---- workspace layout (16B-aligned slabs) ----
    char* p = (char*)d_ws;
    ushort* h1seq = (ushort*)p; p += (size_t)B * T * L * F1 * 2;       // 16.8 MB
    ushort* h2seq = (ushort*)p; p += (size_t)B * T * L * F2 * 2;       // 33.6 MB
    ushort* hping = (ushort*)p; p += (size_t)B * L * F3 * 2;
    ushort* hpong = (ushort*)p; p += (size_t)B * L * F3 * 2;
    float*  cst   = (float*)p;  p += (size_t)B * L * F3 * 4;
    float*  h3bn  = (float*)p;  p += (size_t)B * L * F3 * 4;
    uint4*  wp1   = (uint4*)p;  p += (size_t)2 * 7 * 512 * 16;
    uint4*  wp2   = (uint4*)p;  p += (size_t)4 * 18 * 512 * 16;
    uint4*  wp3   = (uint4*)p;  p += (size_t)8 * 36 * 512 * 16;
    float*  partials = (float*)p; p += (size_t)128 * 32 * 1024 * 4;    // 16.8 MB
    float*  a1 = (float*)p; p += (size_t)B * 1024 * 4;
    float*  a2 = (float*)p; p += (size_t)B * 512 * 4;

    // ---- pack weights (once per launch) ----
    pack_w<<<dim3(F1 / 32, 7), 256, 0, stream>>>(Wx1, 1, Wh1, F1, wp1, 1, 7);
    pack_w<<<dim3(F2 / 32, 18), 256, 0, stream>>>(Wx2, F1, Wh2, F2, wp2, 6, 18);
    pack_w<<<dim3(F3 / 32, 36), 256, 0, stream>>>(Wx3, F2, Wh3, F3, wp3, 12, 36);

    // ---------------- Layer 1: Cin=1, F=64, S0=1, S=7 ----------------
    hipMemsetAsync(hping, 0, (size_t)B * L * F1 * 2, stream);
    hipMemsetAsync(cst, 0, (size_t)B * L * F1 * 4, stream);
    {
        ushort* ha = hping; ushort* hb = hpong;
        dim3 grid(F1 / 32, L / 64, B);
        for (int t = 0; t < T; ++t) {
            gate_mfma<64, true, false><<<grid, 256, 0, stream>>>(
                x + (long)t * L, (long)T * L, 1, 1, 7, ha, F1, wp1, b1,
                cst, hb, h1seq + (long)t * L * F1, (long)T * L * F1,
                g1, be1, m1, v1, L);
            ushort* tmp = ha; ha = hb; hb = tmp;
        }
    }

    // ---------------- Layer 2: Cin=64, F=128, S0=6, S=18 ----------------
    hipMemsetAsync(hping, 0, (size_t)B * L * F2 * 2, stream);
    hipMemsetAsync(cst, 0, (size_t)B * L * F2 * 4, stream);
    {
        ushort* ha = hping; ushort* hb = hpong;
        dim3 grid(F2 / 32, L / 64, B);
        for (int t = 0; t < T; ++t) {
            gate_mfma<64, false, false><<<grid, 256, 0, stream>>>(
                h1seq + (long)t * L * F1, (long)T * L * F1, F1, 6, 18, ha, F2, wp2, b2,
                cst, hb, h2seq + (long)t * L * F2, (long)T * L * F2,
                g2, be2, m2, v2, L);
            ushort* tmp = ha; ha = hb; hb = tmp;
        }
    }

    // ---------------- Layer 3: Cin=128, F=256, S0=12, S=36 ----------------
    hipMemsetAsync(hping, 0, (size_t)B * L * F3 * 2, stream);
    hipMemsetAsync(cst, 0, (size_t)B * L * F3 * 4, stream);
    {
        ushort* ha = hping; ushort* hb = hpong;
        dim3 grid(F3 / 32, L / 128, B);
        for (int t = 0; t < T; ++t) {
            if (t < T - 1)
                gate_mfma<128, false, false><<<grid, 256, 0, stream>>>(
                    h2seq + (long)t * L * F2, (long)T * L * F2, F2, 12, 36, ha, F3, wp3, b3,
                    cst, hb, nullptr, 0, g3, be3, m3, v3, L);
            else
                gate_mfma<128, false, true><<<grid, 256, 0, stream>>>(
                    h2seq + (long)t * L * F2, (long)T * L * F2, F2, 12, 36, ha, F3, wp3, b3,
                    cst, hb, h3bn, (long)L * F3, g3, be3, m3, v3, L);
            ushort* tmp = ha; ha = hb; hb = tmp;
        }
    }

    // ---------------- Dense head ----------------
    {
        const int K = L * F3, KT = 256, nK = K / KT;
        dense_partial<<<dim3(1024 / 128, nK), 256, 0, stream>>>(h3bn, D1, partials, K, 1024, KT);
        dense_reduce_relu<<<(B * 1024) / 256, 256, 0, stream>>>(partials, db1, a1, 1024, nK);
    }
    dense_relu<<<dim3(512 / 256, B), 256, 0, stream>>>(a1, D2, db2, a2, 1024, 512);
    dense_softmax<<<B, 64, 0, stream>>>(a2, D3, db3, (float*)d_out);
}

// Round 4
// 2639.603 us; speedup vs baseline: 5.5823x; 1.1410x over previous
//
#include <hip/hip_runtime.h>
#include <math.h>

#define BN_EPS 1e-3f

typedef unsigned short ushort;
typedef unsigned int uint;
typedef __attribute__((ext_vector_type(8))) short bf16x8;
typedef __attribute__((ext_vector_type(4))) float f32x4;

__device__ __forceinline__ float hsig(float x) {
    return fminf(fmaxf(0.2f * x + 0.5f, 0.f), 1.f);
}
__device__ __forceinline__ ushort f2bf(float f) {
    uint u = __float_as_uint(f);
    u += 0x7fffu + ((u >> 16) & 1u);   // RNE
    return (ushort)(u >> 16);
}

// ---------------------------------------------------------------------------
// pack_w: fp32 weights [3,Cin,4F]+[3,F,4F] -> bf16 fragment-order.
// wp[nblk][step][slot][8], slots = 16*FT, slot = (gate*WN+wn)*64 + q*16 + r,
// element = W[k = step*32 + q*8 + j][n = gate*F + nblk*FT + wn*16 + r].
// steps [0,S0) from Wx (k < 3*Cin valid, else 0), rest from Wh.
// grid: (F/FT, S), block 256. FT in {16,32}.
// ---------------------------------------------------------------------------
__global__ __launch_bounds__(256)
void pack_w(const float* __restrict__ Wx, int Cin,
            const float* __restrict__ Wh, int F,
            uint4* __restrict__ wp, int S0, int S, int FT)
{
    __shared__ ushort Wt[32][136];
    const int nblk = blockIdx.x, step = blockIdx.y;
    const int tid = threadIdx.x;
    const int N4 = 4 * F;
    const int COLS = 4 * FT;
    const int WN = FT >> 4;
    const int SLOTS = 16 * FT;

    for (int idx = tid; idx < 32 * COLS; idx += 256) {
        int kk = idx / COLS, c = idx % COLS;
        int gate = c / FT, fl = c % FT;
        int n = gate * F + nblk * FT + fl;
        float v = 0.f;
        if (step < S0) {
            int ka = step * 32 + kk;
            if (ka < 3 * Cin) v = Wx[(long)ka * N4 + n];
        } else {
            int ka = (step - S0) * 32 + kk;
            v = Wh[(long)ka * N4 + n];
        }
        Wt[kk][c] = f2bf(v);
    }
    __syncthreads();

    for (int s = tid; s < SLOTS; s += 256) {
        int colgrp = s >> 6, qq = (s >> 4) & 3, rr = s & 15;
        int gate = colgrp / WN, wn = colgrp % WN;
        int c = gate * FT + wn * 16 + rr;
        ushort tmp[8];
#pragma unroll
        for (int j = 0; j < 8; ++j) tmp[j] = Wt[qq * 8 + j][c];
        wp[(long)(nblk * S + step) * SLOTS + s] = *(const uint4*)tmp;
    }
}

// ---------------------------------------------------------------------------
// Fused MFMA gate GEMM + LSTM update + optional BN write, one timestep.
// Block: 256 thr = 4 waves arranged WM x WN (WM*WN==4). Tile LT = 16*WM*MT
// rows x COLS = 64*WN cols, where cols = 4 gates x FT=16*WN features.
// Lane's 4 n-frags = the 4 gates of ONE feature -> gate combine thread-local.
// LDS fragment-order, lane reads own 16B slot (conflict-free ds_read_b128).
// grid: (F/FT, L/LT, B).
// ---------------------------------------------------------------------------
template<int WM, int WN, int MT, bool CIN1, bool BNF32>
__global__ __launch_bounds__(256)
void gate_mfma(const void* __restrict__ a0_base,  // layer input at timestep t
               long a0_bstride,                   // batch stride (elements)
               int C0, int S0, int S,
               const ushort* __restrict__ h_old,  // bf16 [B,L,F]
               int F,
               const uint4* __restrict__ wp,      // packed weights
               const float* __restrict__ bias,    // [4F]
               float* __restrict__ c_state,       // fp32 [B,L,F] in-place
               ushort* __restrict__ h_new,        // bf16 [B,L,F]
               void* __restrict__ bn_out,         // may be null
               long bn_bstride,
               const float* __restrict__ bn_g, const float* __restrict__ bn_b,
               const float* __restrict__ bn_m, const float* __restrict__ bn_v,
               int L)
{
    constexpr int LT = 16 * WM * MT;
    constexpr int FT = 16 * WN;
    constexpr int ASLOTS = LT * 4;
    constexpr int BSLOTS = 16 * FT;

    __shared__ ushort As[3][ASLOTS * 8];
    __shared__ ushort Bs[3][BSLOTS * 8];

    const int tid = threadIdx.x;
    const int lane = tid & 63;
    const int wave = tid >> 6;
    const int wn = wave % WN, wm = wave / WN;
    const int q = lane >> 4, r = lane & 15;
    const int f0 = blockIdx.x * FT;
    const int l0 = blockIdx.y * LT;
    const int b = blockIdx.z;

    f32x4 acc[MT][4];
#pragma unroll
    for (int mt = 0; mt < MT; ++mt)
#pragma unroll
        for (int g = 0; g < 4; ++g) acc[mt][g] = (f32x4)(0.f);

    for (int r0 = 0; r0 < S; r0 += 3) {
        const int ns = (S - r0 < 3) ? (S - r0) : 3;
        __syncthreads();
        for (int ss = 0; ss < ns; ++ss) {
            const int step = r0 + ss;
            // ---- B stage: coalesced 16B copies from packed weights ----
            for (int s = tid; s < BSLOTS; s += 256)
                ((uint4*)Bs[ss])[s] = wp[((long)blockIdx.x * S + step) * BSLOTS + s];
            // ---- A stage: im2col into fragment order ----
            for (int s = tid; s < ASLOTS; s += 256) {
                const int mtile = s >> 6, within = s & 63;
                const int qq = within >> 4, rr = within & 15;
                const int row = mtile * 16 + rr;
                if (CIN1 && step < S0) {
                    const float* xb = (const float*)a0_base + (long)b * a0_bstride;
#pragma unroll
                    for (int j = 0; j < 8; ++j) {
                        ushort v = 0;
                        int k = qq * 8 + j;
                        if (k < 3) {
                            int l = l0 + row - 1 + k;
                            if (l >= 0 && l < L) v = f2bf(xb[l]);
                        }
                        As[ss][s * 8 + j] = v;
                    }
                } else {
                    const ushort* Ab;
                    int C, local;
                    if (step < S0) {
                        Ab = (const ushort*)a0_base + (long)b * a0_bstride;
                        C = C0; local = step;
                    } else {
                        Ab = h_old + (long)b * L * F;
                        C = F; local = step - S0;
                    }
                    const int tap = (local * 32) / C;
                    const int c0 = (local * 32) % C;
                    const int l = l0 + row - 1 + tap;
                    uint4 val = {0u, 0u, 0u, 0u};
                    if (l >= 0 && l < L)
                        val = *(const uint4*)&Ab[(long)l * C + c0 + qq * 8];
                    ((uint4*)As[ss])[s] = val;
                }
            }
        }
        __syncthreads();
        for (int ss = 0; ss < ns; ++ss) {
            bf16x8 af[MT], bfr[4];
#pragma unroll
            for (int mt = 0; mt < MT; ++mt)
                af[mt] = *(const bf16x8*)&As[ss][((wm * MT + mt) * 64 + lane) * 8];
#pragma unroll
            for (int g = 0; g < 4; ++g)
                bfr[g] = *(const bf16x8*)&Bs[ss][((g * WN + wn) * 64 + lane) * 8];
#pragma unroll
            for (int mt = 0; mt < MT; ++mt)
#pragma unroll
                for (int g = 0; g < 4; ++g)
                    acc[mt][g] = __builtin_amdgcn_mfma_f32_16x16x32_bf16(
                        af[mt], bfr[g], acc[mt][g], 0, 0, 0);
        }
    }

    // ---- epilogue: bias, gates, state update, optional BN ----
    const int f = f0 + wn * 16 + r;
    const float b_i = bias[f], b_f = bias[F + f];
    const float b_c = bias[2 * F + f], b_o = bias[3 * F + f];
    float sc = 0.f, sh = 0.f;
    if (bn_out) {
        sc = bn_g[f] * rsqrtf(bn_v[f] + BN_EPS);
        sh = bn_b[f] - bn_m[f] * sc;
    }
#pragma unroll
    for (int mt = 0; mt < MT; ++mt) {
#pragma unroll
        for (int reg = 0; reg < 4; ++reg) {
            const int l = l0 + (wm * MT + mt) * 16 + q * 4 + reg;
            const long idx = ((long)b * L + l) * F + f;
            float gi = acc[mt][0][reg] + b_i;
            float gf = acc[mt][1][reg] + b_f;
            float gc = acc[mt][2][reg] + b_c;
            float go = acc[mt][3][reg] + b_o;
            float cold = c_state[idx];
            float cn = hsig(gf) * cold + hsig(gi) * fmaxf(gc, 0.f);
            float hn = hsig(go) * fmaxf(cn, 0.f);
            c_state[idx] = cn;
            h_new[idx] = f2bf(hn);
            if (bn_out) {
                float bv = hn * sc + sh;
                if (BNF32)
                    ((float*)bn_out)[(long)b * bn_bstride + (long)l * F + f] = bv;
                else
                    ((ushort*)bn_out)[(long)b * bn_bstride + (long)l * F + f] = f2bf(bv);
            }
        }
    }
}

// ---------------------------------------------------------------------------
// Dense head. dense_partial: split-K with float4 W loads.
// grid (N/512, K/KT), block 256: tid&127 -> 4 consecutive n, tid>>7 -> m half.
// ---------------------------------------------------------------------------
__global__ __launch_bounds__(256)
void dense_partial(const float* __restrict__ A,   // [32, K]
                   const float* __restrict__ Wt,  // [K, N]
                   float* __restrict__ partials,  // [nK, 32, N]
                   int K, int N, int KT)
{
    __shared__ __align__(16) float A_s[128 * 32];   // KT=128
    const int n0 = blockIdx.x * 512;
    const int k0 = blockIdx.y * KT;
    const int tid = threadIdx.x;

    for (int idx = tid; idx < KT * 32; idx += 256) {
        int k = idx >> 5, m = idx & 31;
        A_s[idx] = A[(long)m * K + k0 + k];
    }
    __syncthreads();

    const int nl = (tid & 127) * 4;
    const int msel = tid >> 7;
    f32x4 acc[16];
#pragma unroll
    for (int i = 0; i < 16; ++i) acc[i] = (f32x4)(0.f);

#pragma unroll 2
    for (int k = 0; k < KT; ++k) {
        const float4 w4 = *(const float4*)&Wt[(long)(k0 + k) * N + n0 + nl];
        const float* ap = &A_s[k * 32 + msel * 16];
#pragma unroll
        for (int mm = 0; mm < 16; ++mm) {
            float a = ap[mm];
            acc[mm][0] += a * w4.x;
            acc[mm][1] += a * w4.y;
            acc[mm][2] += a * w4.z;
            acc[mm][3] += a * w4.w;
        }
    }

#pragma unroll
    for (int mm = 0; mm < 16; ++mm)
        *(f32x4*)&partials[((long)blockIdx.y * 32 + msel * 16 + mm) * N + n0 + nl] = acc[mm];
}

__global__ __launch_bounds__(256)
void dense_reduce_relu(const float* __restrict__ partials,
                       const float* __restrict__ bias,
                       float* __restrict__ out, int N, int nK)
{
    int idx = blockIdx.x * 256 + threadIdx.x;
    int m = idx / N, n = idx % N;
    float s = bias[n];
    for (int j = 0; j < nK; ++j) s += partials[((long)j * 32 + m) * N + n];
    out[idx] = fmaxf(s, 0.f);
}

// D2: K=1024 fits in LDS once; unroll-8 W loads for MLP.
__global__ __launch_bounds__(256)
void dense_relu(const float* __restrict__ A, const float* __restrict__ Wt,
                const float* __restrict__ bias, float* __restrict__ out,
                int K, int N)
{
    __shared__ float A_s[1024];
    int n = blockIdx.x * 256 + threadIdx.x;
    int m = blockIdx.y;
    for (int k = threadIdx.x; k < K; k += 256) A_s[k] = A[(long)m * K + k];
    __syncthreads();
    float acc = 0.f;
#pragma unroll 8
    for (int k = 0; k < K; ++k)
        acc += A_s[k] * Wt[(long)k * N + n];
    out[(long)m * N + n] = fmaxf(acc + bias[n], 0.f);
}

__global__ __launch_bounds__(64)
void dense_softmax(const float* __restrict__ A, const float* __restrict__ W,
                   const float* __restrict__ bias, float* __restrict__ out)
{
    int b = blockIdx.x;
    int tid = threadIdx.x;
    __shared__ float logits[5];

    float part[5] = {0.f, 0.f, 0.f, 0.f, 0.f};
    for (int k = tid; k < 512; k += 64) {
        float a = A[b * 512 + k];
#pragma unroll
        for (int j = 0; j < 5; ++j) part[j] += a * W[k * 5 + j];
    }
#pragma unroll
    for (int j = 0; j < 5; ++j) {
        float v = part[j];
        for (int off = 32; off; off >>= 1) v += __shfl_down(v, off);
        if (tid == 0) logits[j] = v + bias[j];
    }
    __syncthreads();
    if (tid == 0) {
        float mx = logits[0];
        for (int j = 1; j < 5; ++j) mx = fmaxf(mx, logits[j]);
        float s = 0.f, e[5];
        for (int j = 0; j < 5; ++j) { e[j] = expf(logits[j] - mx); s += e[j]; }
        for (int j = 0; j < 5; ++j) out[b * 5 + j] = e[j] / s;
    }
}

extern "C" void kernel_launch(void* const* d_in, const int* in_sizes, int n_in,
                              void* d_out, int out_size, void* d_ws, size_t ws_size,
                              hipStream_t stream)
{
    const int B = 32, T = 32, L = 128;
    const int F1 = 64, F2 = 128, F3 = 256;

    const float* x   = (const float*)d_in[0];
    const float* Wx1 = (const float*)d_in[1];
    const float* Wh1 = (const float*)d_in[2];
    const float* b1  = (const float*)d_in[3];
    const float* Wx2 = (const float*)d_in[4];
    const float* Wh2 = (const float*)d_in[5];
    const float* b2  = (const float*)d_in[6];
    const float* Wx3 = (const float*)d_in[7];
    const float* Wh3 = (const float*)d_in[8];
    const float* b3  = (const float*)d_in[9];
    const float* g1  = (const float*)d_in[10];
    const float* be1 = (const float*)d_in[11];
    const float* m1  = (const float*)d_in[12];
    const float* v1  = (const float*)d_in[13];
    const float* g2  = (const float*)d_in[14];
    const float* be2 = (const float*)d_in[15];
    const float* m2  = (const float*)d_in[16];
    const float* v2  = (const float*)d_in[17];
    const float* g3  = (const float*)d_in[18];
    const float* be3 = (const float*)d_in[19];
    const float* m3  = (const float*)d_in[20];
    const float* v3  = (const float*)d_in[21];
    const float* D1  = (const float*)d_in[22];
    const float* db1 = (const float*)d_in[23];
    const float* D2  = (const float*)d_in[24];
    const float* db2 = (const float*)d_in[25];
    const float* D3  = (const float*)d_in[26];
    const float* db3 = (const float*)d_in[27];
    (void)in_sizes; (void)n_in; (void)out_size; (void)ws_size;

    // ---- workspace layout (16B-aligned slabs) ----
    char* p = (char*)d_ws;
    ushort* h1seq = (ushort*)p; p += (size_t)B * T * L * F1 * 2;       // 16.8 MB
    ushort* h2seq = (ushort*)p; p += (size_t)B * T * L * F2 * 2;       // 33.6 MB
    ushort* hping = (ushort*)p; p += (size_t)B * L * F3 * 2;
    ushort* hpong = (ushort*)p; p += (size_t)B * L * F3 * 2;
    float*  cst   = (float*)p;  p += (size_t)B * L * F3 * 4;
    float*  h3bn  = (float*)p;  p += (size_t)B * L * F3 * 4;
    uint4*  wp1   = (uint4*)p;  p += (size_t)4 * 7 * 256 * 16;         // FT=16
    uint4*  wp2   = (uint4*)p;  p += (size_t)8 * 18 * 256 * 16;        // FT=16
    uint4*  wp3   = (uint4*)p;  p += (size_t)8 * 36 * 512 * 16;        // FT=32
    float*  a1 = (float*)p; p += (size_t)B * 1024 * 4;
    float*  a2 = (float*)p; p += (size_t)B * 512 * 4;
    // partials (256*32*1024 fp32 = 33.5 MB) aliases h2seq, dead after layer 3
    float* partials = (float*)h2seq;

    // ---- pack weights (once per launch) ----
    pack_w<<<dim3(F1 / 16, 7), 256, 0, stream>>>(Wx1, 1, Wh1, F1, wp1, 1, 7, 16);
    pack_w<<<dim3(F2 / 16, 18), 256, 0, stream>>>(Wx2, F1, Wh2, F2, wp2, 6, 18, 16);
    pack_w<<<dim3(F3 / 32, 36), 256, 0, stream>>>(Wx3, F2, Wh3, F3, wp3, 12, 36, 32);

    // ---------------- Layer 1: Cin=1, F=64, S0=1, S=7, FT=16, LT=64 --------
    hipMemsetAsync(hping, 0, (size_t)B * L * F1 * 2, stream);
    hipMemsetAsync(cst, 0, (size_t)B * L * F1 * 4, stream);
    {
        ushort* ha = hping; ushort* hb = hpong;
        dim3 grid(F1 / 16, L / 64, B);   // 256 blocks
        for (int t = 0; t < T; ++t) {
            gate_mfma<4, 1, 1, true, false><<<grid, 256, 0, stream>>>(
                x + (long)t * L, (long)T * L, 1, 1, 7, ha, F1, wp1, b1,
                cst, hb, h1seq + (long)t * L * F1, (long)T * L * F1,
                g1, be1, m1, v1, L);
            ushort* tmp = ha; ha = hb; hb = tmp;
        }
    }

    // ---------------- Layer 2: Cin=64, F=128, S0=6, S=18, FT=16, LT=64 -----
    hipMemsetAsync(hping, 0, (size_t)B * L * F2 * 2, stream);
    hipMemsetAsync(cst, 0, (size_t)B * L * F2 * 4, stream);
    {
        ushort* ha = hping; ushort* hb = hpong;
        dim3 grid(F2 / 16, L / 64, B);   // 512 blocks
        for (int t = 0; t < T; ++t) {
            gate_mfma<4, 1, 1, false, false><<<grid, 256, 0, stream>>>(
                h1seq + (long)t * L * F1, (long)T * L * F1, F1, 6, 18, ha, F2, wp2, b2,
                cst, hb, h2seq + (long)t * L * F2, (long)T * L * F2,
                g2, be2, m2, v2, L);
            ushort* tmp = ha; ha = hb; hb = tmp;
        }
    }

    // ---------------- Layer 3: Cin=128, F=256, S0=12, S=36, FT=32, LT=64 ---
    hipMemsetAsync(hping, 0, (size_t)B * L * F3 * 2, stream);
    hipMemsetAsync(cst, 0, (size_t)B * L * F3 * 4, stream);
    {
        ushort* ha = hping; ushort* hb = hpong;
        dim3 grid(F3 / 32, L / 64, B);   // 512 blocks
        for (int t = 0; t < T; ++t) {
            if (t < T - 1)
                gate_mfma<2, 2, 2, false, false><<<grid, 256, 0, stream>>>(
                    h2seq + (long)t * L * F2, (long)T * L * F2, F2, 12, 36, ha, F3, wp3, b3,
                    cst, hb, nullptr, 0, g3, be3, m3, v3, L);
            else
                gate_mfma<2, 2, 2, false, true><<<grid, 256, 0, stream>>>(
                    h2seq + (long)t * L * F2, (long)T * L * F2, F2, 12, 36, ha, F3, wp3, b3,
                    cst, hb, h3bn, (long)L * F3, g3, be3, m3, v3, L);
            ushort* tmp = ha; ha = hb; hb = tmp;
        }
    }

    // ---------------- Dense head ----------------
    {
        const int K = L * F3, KT = 128, nK = K / KT;   // nK = 256
        dense_partial<<<dim3(1024 / 512, nK), 256, 0, stream>>>(h3bn, D1, partials, K, 1024, KT);
        dense_reduce_relu<<<(B * 1024) / 256, 256, 0, stream>>>(partials, db1, a1, 1024, nK);
    }
    dense_relu<<<dim3(512 / 256, B), 256, 0, stream>>>(a1, D2, db2, a2, 1024, 512);
    dense_softmax<<<B, 64, 0, stream>>>(a2, D3, db3, (float*)d_out);
}

// Round 5
// 1790.368 us; speedup vs baseline: 8.2302x; 1.4743x over previous
//
#include <hip/hip_runtime.h>
#include <math.h>

#define BN_EPS 1e-3f

typedef unsigned short ushort;
typedef unsigned int uint;
typedef __attribute__((ext_vector_type(8))) short bf16x8;
typedef __attribute__((ext_vector_type(4))) float f32x4;

__device__ __forceinline__ float hsig(float x) {
    return fminf(fmaxf(0.2f * x + 0.5f, 0.f), 1.f);
}
__device__ __forceinline__ ushort f2bf(float f) {
    uint u = __float_as_uint(f);
    u += 0x7fffu + ((u >> 16) & 1u);   // RNE
    return (ushort)(u >> 16);
}

// ---------------------------------------------------------------------------
// pack_w: fp32 weights [3,Cin,4F]+[3,F,4F] -> bf16 fragment-order, FT=32.
// wp[nblk][step][slot][8], slot = (gate*2+wn)*64 + q*16 + r,
// element = W[k = step*32 + q*8 + j][n = gate*F + nblk*32 + wn*16 + r].
// steps [0,S0) from Wx (k < 3*Cin valid, else 0), rest from Wh.
// grid: (F/32, S), block 256.
// ---------------------------------------------------------------------------
__global__ __launch_bounds__(256)
void pack_w(const float* __restrict__ Wx, int Cin,
            const float* __restrict__ Wh, int F,
            uint4* __restrict__ wp, int S0, int S)
{
    __shared__ ushort Wt[32][136];
    const int nblk = blockIdx.x, step = blockIdx.y;
    const int tid = threadIdx.x;
    const int N4 = 4 * F;

    for (int idx = tid; idx < 32 * 128; idx += 256) {
        int kk = idx >> 7, c = idx & 127;
        int gate = c >> 5, fl = c & 31;
        int n = gate * F + nblk * 32 + fl;
        float v = 0.f;
        if (step < S0) {
            int ka = step * 32 + kk;
            if (ka < 3 * Cin) v = Wx[(long)ka * N4 + n];
        } else {
            int ka = (step - S0) * 32 + kk;
            v = Wh[(long)ka * N4 + n];
        }
        Wt[kk][c] = f2bf(v);
    }
    __syncthreads();

    for (int s = tid; s < 512; s += 256) {
        int colgrp = s >> 6, qq = (s >> 4) & 3, rr = s & 15;
        int gate = colgrp >> 1, wn = colgrp & 1;
        int c = gate * 32 + wn * 16 + rr;
        ushort tmp[8];
#pragma unroll
        for (int j = 0; j < 8; ++j) tmp[j] = Wt[qq * 8 + j][c];
        wp[(long)(nblk * S + step) * 512 + s] = *(const uint4*)tmp;
    }
}

// ---------------------------------------------------------------------------
// Per-layer config for the diagonal-fused gate kernel.
// ---------------------------------------------------------------------------
struct GateCfg {
    const void* a0;        // layer input base at this layer's timestep
    const ushort* h_old;   // bf16 [B,L,F]
    ushort* h_new;
    const uint4* wp;
    const float* bias;
    float* c_state;        // fp32 [B,L,F]
    void* bn_out;          // may be null
    const float* bn_g; const float* bn_b; const float* bn_m; const float* bn_v;
    long a0_bs;            // batch stride (elements) of a0
    long bn_bs;            // batch stride of bn_out
    int C0, S0, S, F;
    int nf_log2;           // log2(F/32)
    int cin1;              // layer-1 fp32-x input path
    int bnf32;             // bn_out is fp32
    int active;
};

// ---------------------------------------------------------------------------
// Diagonal-fused MFMA gate kernel: one dispatch runs L3@t-2, L2@t-1, L1@t.
// Fixed tile: WM=2, WN=2, MT=2 -> LT=64 rows, FT=32 features (128 cols).
// Block map: [0,512) L3, [512,768) L2, [768,896) L1 (heavy first).
// Lane's 4 n-frags = 4 gates of ONE feature -> gate combine thread-local.
// LDS fragment-order, conflict-free ds_read_b128.
// ---------------------------------------------------------------------------
__global__ __launch_bounds__(256)
void gate_diag(GateCfg c3, GateCfg c2, GateCfg c1, int L)
{
    constexpr int MT = 2;
    constexpr int ASLOTS = 256;   // LT*4
    constexpr int BSLOTS = 512;   // 16*FT

    __shared__ ushort As[3][ASLOTS * 8];
    __shared__ ushort Bs[3][BSLOTS * 8];

    GateCfg c; int tile;
    const int bid = blockIdx.x;
    if (bid < 512)      { c = c3; tile = bid; }
    else if (bid < 768) { c = c2; tile = bid - 512; }
    else                { c = c1; tile = bid - 768; }
    if (!c.active) return;

    const int fblk = tile & ((1 << c.nf_log2) - 1);
    const int rest = tile >> c.nf_log2;
    const int lblk = rest & 1;
    const int b = rest >> 1;

    const int tid = threadIdx.x;
    const int lane = tid & 63;
    const int wave = tid >> 6;
    const int wn = wave & 1, wm = wave >> 1;
    const int q = lane >> 4, r = lane & 15;
    const int f0 = fblk * 32;
    const int l0 = lblk * 64;
    const int F = c.F;
    const int c0shift = 31 - __clz(c.C0 > 0 ? c.C0 : 1);
    const int cFshift = 31 - __clz(F);

    f32x4 acc[MT][4];
#pragma unroll
    for (int mt = 0; mt < MT; ++mt)
#pragma unroll
        for (int g = 0; g < 4; ++g) acc[mt][g] = (f32x4)(0.f);

    const int S = c.S, S0 = c.S0;
    for (int r0 = 0; r0 < S; r0 += 3) {
        const int ns = (S - r0 < 3) ? (S - r0) : 3;
        __syncthreads();
        for (int ss = 0; ss < ns; ++ss) {
            const int step = r0 + ss;
            // ---- B stage: coalesced 16B copies from packed weights ----
            for (int s = tid; s < BSLOTS; s += 256)
                ((uint4*)Bs[ss])[s] = c.wp[((long)fblk * S + step) * BSLOTS + s];
            // ---- A stage: im2col into fragment order ----
            for (int s = tid; s < ASLOTS; s += 256) {
                const int mtile = s >> 6, within = s & 63;
                const int qq = within >> 4, rr = within & 15;
                const int row = mtile * 16 + rr;
                if (c.cin1 && step < S0) {
                    const float* xb = (const float*)c.a0 + (long)b * c.a0_bs;
#pragma unroll
                    for (int j = 0; j < 8; ++j) {
                        ushort v = 0;
                        int k = qq * 8 + j;
                        if (k < 3) {
                            int l = l0 + row - 1 + k;
                            if (l >= 0 && l < L) v = f2bf(xb[l]);
                        }
                        As[ss][s * 8 + j] = v;
                    }
                } else {
                    const ushort* Ab;
                    int local, csh;
                    if (step < S0) {
                        Ab = (const ushort*)c.a0 + (long)b * c.a0_bs;
                        local = step; csh = c0shift;
                    } else {
                        Ab = c.h_old + (long)b * L * F;
                        local = step - S0; csh = cFshift;
                    }
                    const int kb = local * 32;
                    const int tap = kb >> csh;
                    const int ch0 = kb & ((1 << csh) - 1);
                    const int l = l0 + row - 1 + tap;
                    uint4 val = {0u, 0u, 0u, 0u};
                    if (l >= 0 && l < L)
                        val = *(const uint4*)&Ab[((long)l << csh) + ch0 + qq * 8];
                    ((uint4*)As[ss])[s] = val;
                }
            }
        }
        __syncthreads();
        for (int ss = 0; ss < ns; ++ss) {
            bf16x8 af[MT], bfr[4];
#pragma unroll
            for (int mt = 0; mt < MT; ++mt)
                af[mt] = *(const bf16x8*)&As[ss][((wm * MT + mt) * 64 + lane) * 8];
#pragma unroll
            for (int g = 0; g < 4; ++g)
                bfr[g] = *(const bf16x8*)&Bs[ss][((g * 2 + wn) * 64 + lane) * 8];
#pragma unroll
            for (int mt = 0; mt < MT; ++mt)
#pragma unroll
                for (int g = 0; g < 4; ++g)
                    acc[mt][g] = __builtin_amdgcn_mfma_f32_16x16x32_bf16(
                        af[mt], bfr[g], acc[mt][g], 0, 0, 0);
        }
    }

    // ---- epilogue: bias, gates, state update, optional BN ----
    const int f = f0 + wn * 16 + r;
    const float b_i = c.bias[f], b_f = c.bias[F + f];
    const float b_c = c.bias[2 * F + f], b_o = c.bias[3 * F + f];
    float sc = 0.f, sh = 0.f;
    if (c.bn_out) {
        sc = c.bn_g[f] * rsqrtf(c.bn_v[f] + BN_EPS);
        sh = c.bn_b[f] - c.bn_m[f] * sc;
    }
#pragma unroll
    for (int mt = 0; mt < MT; ++mt) {
#pragma unroll
        for (int reg = 0; reg < 4; ++reg) {
            const int l = l0 + (wm * MT + mt) * 16 + q * 4 + reg;
            const long idx = ((long)b * L + l) * F + f;
            float gi = acc[mt][0][reg] + b_i;
            float gf = acc[mt][1][reg] + b_f;
            float gc = acc[mt][2][reg] + b_c;
            float go = acc[mt][3][reg] + b_o;
            float cold = c.c_state[idx];
            float cn = hsig(gf) * cold + hsig(gi) * fmaxf(gc, 0.f);
            float hn = hsig(go) * fmaxf(cn, 0.f);
            c.c_state[idx] = cn;
            c.h_new[idx] = f2bf(hn);
            if (c.bn_out) {
                float bv = hn * sc + sh;
                if (c.bnf32)
                    ((float*)c.bn_out)[(long)b * c.bn_bs + (long)l * F + f] = bv;
                else
                    ((ushort*)c.bn_out)[(long)b * c.bn_bs + (long)l * F + f] = f2bf(bv);
            }
        }
    }
}

// ---------------------------------------------------------------------------
// dense_partial v3: KT=256, N-tile=256, grid (N/256, K/256) = (4,128).
// Thread = 4 consecutive n x 8 m; wave-broadcast LDS A reads; unroll 8 gives
// 8 independent W float4 loads in flight per thread.
// ---------------------------------------------------------------------------
__global__ __launch_bounds__(256)
void dense_partial(const float* __restrict__ A,   // [32, K]
                   const float* __restrict__ Wt,  // [K, N]
                   float* __restrict__ partials,  // [nK, 32, N]
                   int K, int N)
{
    __shared__ __align__(16) float A_s[256 * 32];   // [k][m], 32 KB
    const int n0 = blockIdx.x * 256;
    const int k0 = blockIdx.y * 256;
    const int tid = threadIdx.x;

    for (int idx = tid; idx < 256 * 32; idx += 256) {
        int k = idx >> 5, m = idx & 31;
        A_s[idx] = A[(long)m * K + k0 + k];
    }
    __syncthreads();

    const int nq = (tid & 63) * 4;
    const int mg = tid >> 6;          // m-group: rows mg*8 .. mg*8+7
    f32x4 acc[8];
#pragma unroll
    for (int i = 0; i < 8; ++i) acc[i] = (f32x4)(0.f);

#pragma unroll 8
    for (int k = 0; k < 256; ++k) {
        const float4 w4 = *(const float4*)&Wt[(long)(k0 + k) * N + n0 + nq];
        const float* ap = &A_s[k * 32 + mg * 8];
#pragma unroll
        for (int mm = 0; mm < 8; ++mm) {
            float a = ap[mm];
            acc[mm][0] += a * w4.x;
            acc[mm][1] += a * w4.y;
            acc[mm][2] += a * w4.z;
            acc[mm][3] += a * w4.w;
        }
    }

#pragma unroll
    for (int mm = 0; mm < 8; ++mm)
        *(f32x4*)&partials[((long)blockIdx.y * 32 + mg * 8 + mm) * N + n0 + nq] = acc[mm];
}

__global__ __launch_bounds__(256)
void dense_reduce_relu(const float* __restrict__ partials,
                       const float* __restrict__ bias,
                       float* __restrict__ out, int N, int nK)
{
    int idx = blockIdx.x * 256 + threadIdx.x;
    int m = idx / N, n = idx % N;
    float s = bias[n];
    for (int j = 0; j < nK; ++j) s += partials[((long)j * 32 + m) * N + n];
    out[idx] = fmaxf(s, 0.f);
}

// D2: K=1024 fits in LDS once.
__global__ __launch_bounds__(256)
void dense_relu(const float* __restrict__ A, const float* __restrict__ Wt,
                const float* __restrict__ bias, float* __restrict__ out,
                int K, int N)
{
    __shared__ float A_s[1024];
    int n = blockIdx.x * 256 + threadIdx.x;
    int m = blockIdx.y;
    for (int k = threadIdx.x; k < K; k += 256) A_s[k] = A[(long)m * K + k];
    __syncthreads();
    float acc = 0.f;
#pragma unroll 8
    for (int k = 0; k < K; ++k)
        acc += A_s[k] * Wt[(long)k * N + n];
    out[(long)m * N + n] = fmaxf(acc + bias[n], 0.f);
}

__global__ __launch_bounds__(64)
void dense_softmax(const float* __restrict__ A, const float* __restrict__ W,
                   const float* __restrict__ bias, float* __restrict__ out)
{
    int b = blockIdx.x;
    int tid = threadIdx.x;
    __shared__ float logits[5];

    float part[5] = {0.f, 0.f, 0.f, 0.f, 0.f};
    for (int k = tid; k < 512; k += 64) {
        float a = A[b * 512 + k];
#pragma unroll
        for (int j = 0; j < 5; ++j) part[j] += a * W[k * 5 + j];
    }
#pragma unroll
    for (int j = 0; j < 5; ++j) {
        float v = part[j];
        for (int off = 32; off; off >>= 1) v += __shfl_down(v, off);
        if (tid == 0) logits[j] = v + bias[j];
    }
    __syncthreads();
    if (tid == 0) {
        float mx = logits[0];
        for (int j = 1; j < 5; ++j) mx = fmaxf(mx, logits[j]);
        float s = 0.f, e[5];
        for (int j = 0; j < 5; ++j) { e[j] = expf(logits[j] - mx); s += e[j]; }
        for (int j = 0; j < 5; ++j) out[b * 5 + j] = e[j] / s;
    }
}

extern "C" void kernel_launch(void* const* d_in, const int* in_sizes, int n_in,
                              void* d_out, int out_size, void* d_ws, size_t ws_size,
                              hipStream_t stream)
{
    const int B = 32, T = 32, L = 128;
    const int F1 = 64, F2 = 128, F3 = 256;

    const float* x   = (const float*)d_in[0];
    const float* Wx1 = (const float*)d_in[1];
    const float* Wh1 = (const float*)d_in[2];
    const float* b1  = (const float*)d_in[3];
    const float* Wx2 = (const float*)d_in[4];
    const float* Wh2 = (const float*)d_in[5];
    const float* b2  = (const float*)d_in[6];
    const float* Wx3 = (const float*)d_in[7];
    const float* Wh3 = (const float*)d_in[8];
    const float* b3  = (const float*)d_in[9];
    const float* g1  = (const float*)d_in[10];
    const float* be1 = (const float*)d_in[11];
    const float* m1  = (const float*)d_in[12];
    const float* v1  = (const float*)d_in[13];
    const float* g2  = (const float*)d_in[14];
    const float* be2 = (const float*)d_in[15];
    const float* m2  = (const float*)d_in[16];
    const float* v2  = (const float*)d_in[17];
    const float* g3  = (const float*)d_in[18];
    const float* be3 = (const float*)d_in[19];
    const float* m3  = (const float*)d_in[20];
    const float* v3  = (const float*)d_in[21];
    const float* D1  = (const float*)d_in[22];
    const float* db1 = (const float*)d_in[23];
    const float* D2  = (const float*)d_in[24];
    const float* db2 = (const float*)d_in[25];
    const float* D3  = (const float*)d_in[26];
    const float* db3 = (const float*)d_in[27];
    (void)in_sizes; (void)n_in; (void)out_size; (void)ws_size;

    // ---- workspace layout ----
    char* p = (char*)d_ws;
    ushort* h1seq = (ushort*)p; p += (size_t)B * T * L * F1 * 2;       // 16.8 MB
    ushort* h2seq = (ushort*)p; p += (size_t)B * T * L * F2 * 2;       // 33.6 MB
    ushort* h1a = (ushort*)p; p += (size_t)B * L * F1 * 2;
    ushort* h1b = (ushort*)p; p += (size_t)B * L * F1 * 2;
    ushort* h2a = (ushort*)p; p += (size_t)B * L * F2 * 2;
    ushort* h2b = (ushort*)p; p += (size_t)B * L * F2 * 2;
    ushort* h3a = (ushort*)p; p += (size_t)B * L * F3 * 2;
    ushort* h3b = (ushort*)p; p += (size_t)B * L * F3 * 2;
    float*  c1s = (float*)p; p += (size_t)B * L * F1 * 4;
    float*  c2s = (float*)p; p += (size_t)B * L * F2 * 4;
    float*  c3s = (float*)p; p += (size_t)B * L * F3 * 4;
    float*  h3bn = (float*)p; p += (size_t)B * L * F3 * 4;
    uint4*  wp1 = (uint4*)p; p += (size_t)2 * 7 * 512 * 16;
    uint4*  wp2 = (uint4*)p; p += (size_t)4 * 18 * 512 * 16;
    uint4*  wp3 = (uint4*)p; p += (size_t)8 * 36 * 512 * 16;
    float*  a1 = (float*)p; p += (size_t)B * 1024 * 4;
    float*  a2 = (float*)p; p += (size_t)B * 512 * 4;
    float* partials = (float*)h2seq;   // 128*32*1024*4 = 16.8 MB, dead-slab alias

    // ---- pack weights ----
    pack_w<<<dim3(2, 7), 256, 0, stream>>>(Wx1, 1, Wh1, F1, wp1, 1, 7);
    pack_w<<<dim3(4, 18), 256, 0, stream>>>(Wx2, F1, Wh2, F2, wp2, 6, 18);
    pack_w<<<dim3(8, 36), 256, 0, stream>>>(Wx3, F2, Wh3, F3, wp3, 12, 36);

    // ---- zero initial states ----
    hipMemsetAsync(h1a, 0, (size_t)B * L * F1 * 2, stream);
    hipMemsetAsync(h2a, 0, (size_t)B * L * F2 * 2, stream);
    hipMemsetAsync(h3a, 0, (size_t)B * L * F3 * 2, stream);
    hipMemsetAsync(c1s, 0, (size_t)B * L * F1 * 4, stream);
    hipMemsetAsync(c2s, 0, (size_t)B * L * F2 * 4, stream);
    hipMemsetAsync(c3s, 0, (size_t)B * L * F3 * 4, stream);

    // ---- diagonal schedule: dispatch d runs L1@d, L2@d-1, L3@d-2 ----
    for (int d = 0; d < T + 2; ++d) {
        GateCfg c1c = {}, c2c = {}, c3c = {};

        int t1 = d;
        if (t1 >= 0 && t1 < T) {
            c1c.active = 1; c1c.cin1 = 1; c1c.bnf32 = 0;
            c1c.a0 = x + (long)t1 * L; c1c.a0_bs = (long)T * L;
            c1c.C0 = 1; c1c.S0 = 1; c1c.S = 7; c1c.F = F1; c1c.nf_log2 = 1;
            c1c.h_old = (t1 & 1) ? h1b : h1a;
            c1c.h_new = (t1 & 1) ? h1a : h1b;
            c1c.wp = wp1; c1c.bias = b1; c1c.c_state = c1s;
            c1c.bn_out = h1seq + (long)t1 * L * F1; c1c.bn_bs = (long)T * L * F1;
            c1c.bn_g = g1; c1c.bn_b = be1; c1c.bn_m = m1; c1c.bn_v = v1;
        }
        int t2 = d - 1;
        if (t2 >= 0 && t2 < T) {
            c2c.active = 1; c2c.cin1 = 0; c2c.bnf32 = 0;
            c2c.a0 = h1seq + (long)t2 * L * F1; c2c.a0_bs = (long)T * L * F1;
            c2c.C0 = F1; c2c.S0 = 6; c2c.S = 18; c2c.F = F2; c2c.nf_log2 = 2;
            c2c.h_old = (t2 & 1) ? h2b : h2a;
            c2c.h_new = (t2 & 1) ? h2a : h2b;
            c2c.wp = wp2; c2c.bias = b2; c2c.c_state = c2s;
            c2c.bn_out = h2seq + (long)t2 * L * F2; c2c.bn_bs = (long)T * L * F2;
            c2c.bn_g = g2; c2c.bn_b = be2; c2c.bn_m = m2; c2c.bn_v = v2;
        }
        int t3 = d - 2;
        if (t3 >= 0 && t3 < T) {
            c3c.active = 1; c3c.cin1 = 0; c3c.bnf32 = 1;
            c3c.a0 = h2seq + (long)t3 * L * F2; c3c.a0_bs = (long)T * L * F2;
            c3c.C0 = F2; c3c.S0 = 12; c3c.S = 36; c3c.F = F3; c3c.nf_log2 = 3;
            c3c.h_old = (t3 & 1) ? h3b : h3a;
            c3c.h_new = (t3 & 1) ? h3a : h3b;
            c3c.wp = wp3; c3c.bias = b3; c3c.c_state = c3s;
            c3c.bn_out = (t3 == T - 1) ? (void*)h3bn : nullptr;
            c3c.bn_bs = (long)L * F3;
            c3c.bn_g = g3; c3c.bn_b = be3; c3c.bn_m = m3; c3c.bn_v = v3;
        }
        gate_diag<<<896, 256, 0, stream>>>(c3c, c2c, c1c, L);
    }

    // ---- dense head ----
    {
        const int K = L * F3;              // 32768
        dense_partial<<<dim3(4, 128), 256, 0, stream>>>(h3bn, D1, partials, K, 1024);
        dense_reduce_relu<<<(B * 1024) / 256, 256, 0, stream>>>(partials, db1, a1, 1024, 128);
    }
    dense_relu<<<dim3(512 / 256, B), 256, 0, stream>>>(a1, D2, db2, a2, 1024, 512);
    dense_softmax<<<B, 64, 0, stream>>>(a2, D3, db3, (float*)d_out);
}